// Round 12
// baseline (249.434 us; speedup 1.0000x reference)
//
#include <hip/hip_runtime.h>
#include <math.h>

#define NTH 256
#define NTHM 128
#define LAM 0.01f
#define WS_WT_BYTES 589824   // 4 planes * 8 blocks * 96*96 * 2B (bf16 W^T)

typedef __attribute__((ext_vector_type(8))) short short8;
typedef __attribute__((ext_vector_type(8))) unsigned short ushort8;
typedef __attribute__((ext_vector_type(4))) float f32x4;
typedef __attribute__((ext_vector_type(4))) unsigned int uint4v;

__device__ __forceinline__ ushort f2bf(float f) {
    union { float f; unsigned u; } c; c.f = f;
    unsigned u = c.u;
    u += 0x7fffu + ((u >> 16) & 1u);   // round-to-nearest-even
    return (ushort)(u >> 16);
}
__device__ __forceinline__ float bf2f(ushort h) {
    union { unsigned u; float f; } c; c.u = ((unsigned)h) << 16; return c.f;
}

// Spectrum storage: packed bf16 (re lo16, im hi16), one uint per mode, in the
// first 8 KB of each row's 16 KB slot. Word 0 = {re(mode0) lo, re(mode2048) hi}.

// LDS index padding for FFT stages.
__device__ __forceinline__ int pad(int i) { return i + (i >> 3); }
#define FFT_LDS_SZ 2304

// ---- complex helpers -------------------------------------------------------
__device__ __forceinline__ float2 cadd(float2 a, float2 b) { return make_float2(a.x + b.x, a.y + b.y); }
__device__ __forceinline__ float2 csub(float2 a, float2 b) { return make_float2(a.x - b.x, a.y - b.y); }
__device__ __forceinline__ float2 cmul(float2 a, float2 b) { return make_float2(a.x * b.x - a.y * b.y, a.x * b.y + a.y * b.x); }
__device__ __forceinline__ float2 cjrot(float2 a, float sign) { return make_float2(-sign * a.y, sign * a.x); } // sign*i*a

// ---------------------------------------------------------------------------
// Radix-8 butterfly on registers (Ns=1 form: no input twiddle).
// ---------------------------------------------------------------------------
__device__ __forceinline__ void radix8_bfly(const float2 t[8], float2 o[8], float sign) {
    float2 apc = cadd(t[0], t[4]), amc = csub(t[0], t[4]);
    float2 bpd = cadd(t[2], t[6]), bmd = csub(t[2], t[6]);
    float2 e0 = cadd(apc, bpd), e2 = csub(apc, bpd);
    float2 jb = cjrot(bmd, sign);
    float2 e1 = cadd(amc, jb), e3 = csub(amc, jb);
    float2 apc2 = cadd(t[1], t[5]), amc2 = csub(t[1], t[5]);
    float2 bpd2 = cadd(t[3], t[7]), bmd2 = csub(t[3], t[7]);
    float2 q0 = cadd(apc2, bpd2), q2 = csub(apc2, bpd2);
    float2 jb2 = cjrot(bmd2, sign);
    float2 q1 = cadd(amc2, jb2), q3 = csub(amc2, jb2);
    const float H = 0.70710678118654752f;
    q1 = cmul(q1, make_float2(H, sign * H));
    q2 = cjrot(q2, sign);
    q3 = cmul(q3, make_float2(-H, sign * H));
    o[0] = cadd(e0, q0); o[1] = cadd(e1, q1); o[2] = cadd(e2, q2); o[3] = cadd(e3, q3);
    o[4] = csub(e0, q0); o[5] = csub(e1, q1); o[6] = csub(e2, q2); o[7] = csub(e3, q3);
}

// ---------------------------------------------------------------------------
// Middle radix-8 Stockham stage (LDS -> LDS), with input twiddles.
// ---------------------------------------------------------------------------
__device__ __forceinline__ void radix8_stage(const float2* __restrict__ src,
                                             float2* __restrict__ dst,
                                             int tid, int Ns, float sign) {
    const int u = tid;
    const int r = u & (Ns - 1);
    float2 t[8];
    t[0] = src[pad(u)];
    t[1] = src[pad(u + 256)];
    t[2] = src[pad(u + 512)];
    t[3] = src[pad(u + 768)];
    t[4] = src[pad(u + 1024)];
    t[5] = src[pad(u + 1280)];
    t[6] = src[pad(u + 1536)];
    t[7] = src[pad(u + 1792)];
    {
        float ang = sign * ((float)M_PI / (4.0f * (float)Ns)) * (float)r;
        float s1, c1;
        __sincosf(ang, &s1, &c1);
        float2 w1 = make_float2(c1, s1);
        float2 w2 = cmul(w1, w1);
        float2 w3 = cmul(w2, w1);
        float2 w4 = cmul(w2, w2);
        float2 w5 = cmul(w4, w1);
        float2 w6 = cmul(w4, w2);
        float2 w7 = cmul(w4, w3);
        t[1] = cmul(t[1], w1); t[2] = cmul(t[2], w2); t[3] = cmul(t[3], w3);
        t[4] = cmul(t[4], w4); t[5] = cmul(t[5], w5); t[6] = cmul(t[6], w6);
        t[7] = cmul(t[7], w7);
    }
    float2 o[8];
    radix8_bfly(t, o, sign);
    const int d = ((u - r) << 3) + r;
    dst[pad(d)]          = o[0];
    dst[pad(d + Ns)]     = o[1];
    dst[pad(d + 2 * Ns)] = o[2];
    dst[pad(d + 3 * Ns)] = o[3];
    dst[pad(d + 4 * Ns)] = o[4];
    dst[pad(d + 5 * Ns)] = o[5];
    dst[pad(d + 6 * Ns)] = o[6];
    dst[pad(d + 7 * Ns)] = o[7];
}

__device__ __forceinline__ void radix4_final(const float2* __restrict__ src,
                                             float2* __restrict__ dst,
                                             int tid, float sign) {
    for (int u = tid; u < 512; u += NTH) {
        float2 x0 = src[pad(u)];
        float2 x1 = src[pad(u + 512)];
        float2 x2 = src[pad(u + 1024)];
        float2 x3 = src[pad(u + 1536)];
        float ang = sign * ((float)M_PI / 1024.0f) * (float)u;
        float s1, c1;
        __sincosf(ang, &s1, &c1);
        float2 w1 = make_float2(c1, s1);
        float2 w2 = cmul(w1, w1);
        float2 w3 = cmul(w2, w1);
        x1 = cmul(x1, w1); x2 = cmul(x2, w2); x3 = cmul(x3, w3);
        float2 apc = cadd(x0, x2), amc = csub(x0, x2);
        float2 bpd = cadd(x1, x3), bmd = csub(x1, x3);
        float2 e = cjrot(bmd, sign);
        dst[pad(u)]        = cadd(apc, bpd);
        dst[pad(u + 512)]  = cadd(amc, e);
        dst[pad(u + 1024)] = csub(apc, bpd);
        dst[pad(u + 1536)] = csub(amc, e);
    }
}

// ---------------------------------------------------------------------------
// Forward rfft per row (ortho); output = packed bf16 spectrum (8 KB / row).
// ---------------------------------------------------------------------------
__global__ __launch_bounds__(NTH, 4) void k_rfft_fwd(const float* __restrict__ x,
                                                     float* __restrict__ out) {
    __shared__ float2 bufA[FFT_LDS_SZ];
    __shared__ float2 bufB[FFT_LDS_SZ];
    const int row = blockIdx.x;
    const float* xr = x + (size_t)row * 4096;
    unsigned* srow = (unsigned*)(out + (size_t)row * 4096);
    const int tid = threadIdx.x;

    // ---- fused stage 1 (radix-8, Ns=1) straight from global
    {
        float2 t[8], o[8];
#pragma unroll
        for (int j = 0; j < 8; ++j)
            t[j] = *(const float2*)(xr + 2 * (tid + 256 * j));
        radix8_bfly(t, o, -1.0f);
#pragma unroll
        for (int j = 0; j < 8; ++j)
            bufB[pad(8 * tid + j)] = o[j];
    }
    __syncthreads();
    radix8_stage(bufB, bufA, tid, 8, -1.0f);
    __syncthreads();
    radix8_stage(bufA, bufB, tid, 64, -1.0f);
    __syncthreads();
    radix4_final(bufB, bufA, tid, -1.0f);
    __syncthreads();
    float2* Z = bufA;

    // ---- pack to bf16; twiddle chained by rotation of -pi/8 per iteration
    const float scale = 1.0f / 64.0f;
    float s0, c0;
    __sincosf(-(float)M_PI * (float)tid / 2048.0f, &s0, &c0);
    float2 w = make_float2(c0, s0);
    const float2 stepw = make_float2(0.92387953251128674f, -0.38268343236508978f);
    for (int k = tid; k <= 2048; k += NTH) {
        float2 zk = Z[pad(k & 2047)];
        float2 zn = Z[pad((2048 - k) & 2047)];
        float Ar = 0.5f * (zk.x + zn.x), Ai = 0.5f * (zk.y - zn.y);
        float Br = 0.5f * (zk.x - zn.x), Bi = 0.5f * (zk.y + zn.y);
        float wBr = w.x * Br - w.y * Bi;
        float wBi = w.x * Bi + w.y * Br;
        float Xr = (Ar + wBi) * scale;
        float Xi = (Ai - wBr) * scale;
        if (k == 0)          ((ushort*)srow)[0] = f2bf(Xr);
        else if (k == 2048)  ((ushort*)srow)[1] = f2bf(Xr);
        else                 srow[k] = (unsigned)f2bf(Xr) | ((unsigned)f2bf(Xi) << 16);
        w = cmul(w, stepw);
    }
}

// ---------------------------------------------------------------------------
// Weight preprocessing: fp32 W[a][n][i][o] -> bf16 W^T in ws: [a][n][o][i].
// ---------------------------------------------------------------------------
__global__ __launch_bounds__(NTH) void k_prep(
    const float* __restrict__ w1_re, const float* __restrict__ w1_im,
    const float* __restrict__ w2_re, const float* __restrict__ w2_im,
    ushort* __restrict__ wt) {
    int gid = blockIdx.x * NTH + threadIdx.x;   // 0 .. 294911
    if (gid >= 294912) return;
    int a   = gid / 73728;
    int rem = gid - a * 73728;
    int n   = rem / 9216;
    int r2  = rem - n * 9216;
    int o   = r2 / 96;
    int i   = r2 - o * 96;
    const float* src = (a == 0) ? w1_re : (a == 1) ? w1_im : (a == 2) ? w2_re : w2_im;
    wt[gid] = f2bf(src[(n * 96 + i) * 96 + o]);
}

// ---------------------------------------------------------------------------
// MFMA mixer v11: mix10 + deep issue / software double-buffering.
//  - Stage: all 48 loads issued before any LDS write (1 latency, not 4).
//  - Weights: ping-pong wr[2][6]; batch kk+1 issued BEFORE kk's 48 MFMAs;
//    layer-2 batch 0 issued before crelu (hides under VALU+LDS work).
//  - Everything else identical to mix10 (128-B segments both sides).
// Grid (33, 8, 16) x 128 thr (2 waves x 32 modes), barrier-free.
// ---------------------------------------------------------------------------
__global__ __launch_bounds__(NTHM, 2) void k_mix11(
    float* __restrict__ io, const ushort* __restrict__ wt,
    const float* __restrict__ b1_re, const float* __restrict__ b1_im,
    const float* __restrict__ b2_re, const float* __restrict__ b2_im) {
    __shared__ __align__(16) ushort xb[2][64][104];   // 26624 B (reused as out-staging)

    const int mt = blockIdx.x;
    const int n  = blockIdx.y;
    const int b  = blockIdx.z;
    const int tid  = threadIdx.x;
    const int lane = tid & 63;
    const int wv   = tid >> 6;            // 0..1
    const int m0 = mt * 64;
    const int ws0 = wv * 32;              // wave's private 32-row stripe
    unsigned* sb = (unsigned*)(io + ((size_t)b * 768 + (size_t)n * 96) * 4096);

    const int lc = lane & 15;
    const int hi = lane >> 4;
    const int ll = lane & 31;             // mode within wave stripe
    const int ch = lane >> 5;             // channel phase (0/1)
    const int mbase = m0 + ws0;
    const bool interior = (mbase >= 1) && (mbase + 31 < 2048);

    // ---- stage: 48 loads issued up-front, then unpack to LDS
    {
        const int m = mbase + ll;
        const unsigned* src = sb + ((m >= 1 && m < 2048) ? m : 0);
        unsigned v[48];
#pragma unroll
        for (int t = 0; t < 48; ++t)
            v[t] = src[(size_t)(ch + 2 * t) * 4096];
        if (interior) {
#pragma unroll
            for (int t = 0; t < 48; ++t) {
                const int i = ch + 2 * t;
                xb[0][ws0 + ll][i] = (ushort)v[t];
                xb[1][ws0 + ll][i] = (ushort)(v[t] >> 16);
            }
        } else {
#pragma unroll
            for (int t = 0; t < 48; ++t) {
                const int i = ch + 2 * t;
                unsigned w = v[t];
                ushort lo = (ushort)w, h16 = (ushort)(w >> 16);
                ushort re = (m == 2048) ? h16 : (m < 2048 ? lo : (ushort)0);
                ushort im = (m >= 1 && m < 2048) ? h16 : (ushort)0;
                xb[0][ws0 + ll][i] = re;
                xb[1][ws0 + ll][i] = im;
            }
        }
    }

    const int kl = 8 * hi;
    const int mr0 = ws0 + lc;
    const int mr1 = ws0 + 16 + lc;
    const ushort* wn  = wt + (size_t)n * 9216;        // w1_re^T; +73728 per plane
    const ushort* wn2 = wn + 2 * 73728;               // w2_re^T

    float b1r[6], b1i[6];
#pragma unroll
    for (int nt = 0; nt < 6; ++nt) {
        b1r[nt] = b1_re[n * 96 + nt * 16 + lc];
        b1i[nt] = b1_im[n * 96 + nt * 16 + lc];
    }

    f32x4 accR[2][6], accI[2][6];
    const f32x4 zero = {0.f, 0.f, 0.f, 0.f};
#pragma unroll
    for (int t2 = 0; t2 < 2; ++t2)
#pragma unroll
        for (int nt = 0; nt < 6; ++nt) { accR[t2][nt] = zero; accI[t2][nt] = zero; }

    // weight ping-pong buffers (indices compile-time after unroll)
    short8 wr[2][6], wi[2][6];
#define LOADW(base, kkv, buf)                                              \
    {                                                                      \
        const int k0_ = (kkv) * 32 + kl;                                   \
        _Pragma("unroll")                                                  \
        for (int nt_ = 0; nt_ < 6; ++nt_) {                                \
            const ushort* wp_ = (base) + (nt_ * 16 + lc) * 96 + k0_;       \
            wr[buf][nt_] = *(const short8*)(wp_);                          \
            wi[buf][nt_] = *(const short8*)(wp_ + 73728);                  \
        }                                                                  \
    }

    // ---- layer 1: double-buffered weight batches
    LOADW(wn, 0, 0);
#pragma unroll
    for (int kk = 0; kk < 3; ++kk) {
        const int cur = kk & 1;
        if (kk < 2) LOADW(wn, kk + 1, cur ^ 1);     // in flight during MFMAs
        const int k0 = kk * 32 + kl;
        short8 arA = *(const short8*)&xb[0][mr0][k0];
        short8 aiA = *(const short8*)&xb[1][mr0][k0];
        short8 arB = *(const short8*)&xb[0][mr1][k0];
        short8 aiB = *(const short8*)&xb[1][mr1][k0];
        short8 naiA, naiB;
#pragma unroll
        for (int j = 0; j < 8; ++j) { naiA[j] = aiA[j] ^ (short)0x8000; naiB[j] = aiB[j] ^ (short)0x8000; }
#pragma unroll
        for (int nt = 0; nt < 6; ++nt) {
            accR[0][nt] = __builtin_amdgcn_mfma_f32_16x16x32_bf16(arA,  wr[cur][nt], accR[0][nt], 0, 0, 0);
            accR[0][nt] = __builtin_amdgcn_mfma_f32_16x16x32_bf16(naiA, wi[cur][nt], accR[0][nt], 0, 0, 0);
            accI[0][nt] = __builtin_amdgcn_mfma_f32_16x16x32_bf16(arA,  wi[cur][nt], accI[0][nt], 0, 0, 0);
            accI[0][nt] = __builtin_amdgcn_mfma_f32_16x16x32_bf16(aiA,  wr[cur][nt], accI[0][nt], 0, 0, 0);
            accR[1][nt] = __builtin_amdgcn_mfma_f32_16x16x32_bf16(arB,  wr[cur][nt], accR[1][nt], 0, 0, 0);
            accR[1][nt] = __builtin_amdgcn_mfma_f32_16x16x32_bf16(naiB, wi[cur][nt], accR[1][nt], 0, 0, 0);
            accI[1][nt] = __builtin_amdgcn_mfma_f32_16x16x32_bf16(arB,  wi[cur][nt], accI[1][nt], 0, 0, 0);
            accI[1][nt] = __builtin_amdgcn_mfma_f32_16x16x32_bf16(aiB,  wr[cur][nt], accI[1][nt], 0, 0, 0);
        }
    }

    // prefetch layer-2 batch 0 before crelu (hides under VALU+LDS below)
    LOADW(wn2, 0, 0);

    // crelu -> h into own stripes (same-wave LDS dependency only)
#pragma unroll
    for (int t2 = 0; t2 < 2; ++t2)
#pragma unroll
        for (int nt = 0; nt < 6; ++nt) {
#pragma unroll
            for (int q = 0; q < 4; ++q) {
                int mm = ws0 + t2 * 16 + 4 * hi + q;
                xb[0][mm][nt * 16 + lc] = f2bf(fmaxf(accR[t2][nt][q] + b1r[nt], 0.f));
                xb[1][mm][nt * 16 + lc] = f2bf(fmaxf(accI[t2][nt][q] + b1i[nt], 0.f));
            }
        }

    // ---- layer 2: double-buffered weight batches
#pragma unroll
    for (int t2 = 0; t2 < 2; ++t2)
#pragma unroll
        for (int nt = 0; nt < 6; ++nt) { accR[t2][nt] = zero; accI[t2][nt] = zero; }
#pragma unroll
    for (int kk = 0; kk < 3; ++kk) {
        const int cur = kk & 1;
        if (kk < 2) LOADW(wn2, kk + 1, cur ^ 1);
        const int k0 = kk * 32 + kl;
        short8 arA = *(const short8*)&xb[0][mr0][k0];
        short8 aiA = *(const short8*)&xb[1][mr0][k0];
        short8 arB = *(const short8*)&xb[0][mr1][k0];
        short8 aiB = *(const short8*)&xb[1][mr1][k0];
        short8 naiA, naiB;
#pragma unroll
        for (int j = 0; j < 8; ++j) { naiA[j] = aiA[j] ^ (short)0x8000; naiB[j] = aiB[j] ^ (short)0x8000; }
#pragma unroll
        for (int nt = 0; nt < 6; ++nt) {
            accR[0][nt] = __builtin_amdgcn_mfma_f32_16x16x32_bf16(arA,  wr[cur][nt], accR[0][nt], 0, 0, 0);
            accR[0][nt] = __builtin_amdgcn_mfma_f32_16x16x32_bf16(naiA, wi[cur][nt], accR[0][nt], 0, 0, 0);
            accI[0][nt] = __builtin_amdgcn_mfma_f32_16x16x32_bf16(arA,  wi[cur][nt], accI[0][nt], 0, 0, 0);
            accI[0][nt] = __builtin_amdgcn_mfma_f32_16x16x32_bf16(aiA,  wr[cur][nt], accI[0][nt], 0, 0, 0);
            accR[1][nt] = __builtin_amdgcn_mfma_f32_16x16x32_bf16(arB,  wr[cur][nt], accR[1][nt], 0, 0, 0);
            accR[1][nt] = __builtin_amdgcn_mfma_f32_16x16x32_bf16(naiB, wi[cur][nt], accR[1][nt], 0, 0, 0);
            accI[1][nt] = __builtin_amdgcn_mfma_f32_16x16x32_bf16(arB,  wi[cur][nt], accI[1][nt], 0, 0, 0);
            accI[1][nt] = __builtin_amdgcn_mfma_f32_16x16x32_bf16(aiB,  wr[cur][nt], accI[1][nt], 0, 0, 0);
        }
    }
#undef LOADW

    // ---- softshrink + store
    float b2r[6], b2i[6];
#pragma unroll
    for (int nt = 0; nt < 6; ++nt) {
        b2r[nt] = b2_re[n * 96 + nt * 16 + lc];
        b2i[nt] = b2_im[n * 96 + nt * 16 + lc];
    }
    if (interior) {
        // wave-private out-staging: chans 0..47 in this wave's plane-0 chunk,
        // chans 48..95 in its plane-1 chunk ([48][33] uints each, 1584<=1664).
        unsigned* ob0 = (unsigned*)&xb[0][ws0][0];
        unsigned* ob1 = (unsigned*)&xb[1][ws0][0];
#pragma unroll
        for (int t2 = 0; t2 < 2; ++t2)
#pragma unroll
            for (int nt = 0; nt < 6; ++nt) {
                unsigned* obp = (nt < 3) ? ob0 : ob1;
                const int crow = nt * 16 + lc - ((nt < 3) ? 0 : 48);
#pragma unroll
                for (int q = 0; q < 4; ++q) {
                    float vr = accR[t2][nt][q] + b2r[nt];
                    float vi = accI[t2][nt][q] + b2i[nt];
                    float sr = copysignf(fmaxf(fabsf(vr) - LAM, 0.f), vr);
                    float si = copysignf(fmaxf(fabsf(vi) - LAM, 0.f), vi);
                    obp[crow * 33 + (t2 * 16 + 4 * hi + q)] =
                        (unsigned)f2bf(sr) | ((unsigned)f2bf(si) << 16);
                }
            }
        // linear 128-B stores: 12 instructions x (8 rows x 128 B)
#pragma unroll
        for (int s = 0; s < 12; ++s) {
            const int g   = s * 64 + lane;     // 4-uint group, 8 per chan-row
            const int row = g >> 3;            // chan 0..95
            const int wih = g & 7;             // which 16 B within the 128 B
            const unsigned* lsrc = ((row < 48) ? ob0 : ob1) +
                                   (row - ((row < 48) ? 0 : 48)) * 33 + wih * 4;
            uint4v pk;
            pk[0] = lsrc[0]; pk[1] = lsrc[1]; pk[2] = lsrc[2]; pk[3] = lsrc[3];
            *(uint4v*)(sb + (size_t)row * 4096 + mbase + wih * 4) = pk;
        }
    } else {
        // scalar edge path (modes 0 / >=2048)
#pragma unroll
        for (int t2 = 0; t2 < 2; ++t2) {
            const int mq = mbase + t2 * 16 + 4 * hi;
#pragma unroll
            for (int nt = 0; nt < 6; ++nt) {
                float sr[4], si[4];
#pragma unroll
                for (int q = 0; q < 4; ++q) {
                    float vr = accR[t2][nt][q] + b2r[nt];
                    float vi = accI[t2][nt][q] + b2i[nt];
                    sr[q] = copysignf(fmaxf(fabsf(vr) - LAM, 0.f), vr);
                    si[q] = copysignf(fmaxf(fabsf(vi) - LAM, 0.f), vi);
                }
                unsigned* row = sb + (size_t)(nt * 16 + lc) * 4096;
#pragma unroll
                for (int q = 0; q < 4; ++q) {
                    int m = mq + q;
                    if (m == 0)          ((ushort*)row)[0] = f2bf(sr[q]);
                    else if (m == 2048)  ((ushort*)row)[1] = f2bf(sr[q]);
                    else if (m < 2048)   row[m] = (unsigned)f2bf(sr[q]) | ((unsigned)f2bf(si[q]) << 16);
                }
            }
        }
    }
}

// ---------------------------------------------------------------------------
// Fallback mixer (no ws dependency), bf16 packed spectrum io.
// ---------------------------------------------------------------------------
__global__ __launch_bounds__(NTH) void k_mix_fallback(
    float* __restrict__ io,
    const float* __restrict__ w1_re, const float* __restrict__ w1_im,
    const float* __restrict__ w2_re, const float* __restrict__ w2_im,
    const float* __restrict__ b1_re, const float* __restrict__ b1_im,
    const float* __restrict__ b2_re, const float* __restrict__ b2_im) {
    __shared__ __align__(16) ushort xb[2][64][96];
    __shared__ __align__(16) ushort wb[2][96][104];

    const int mt = blockIdx.x;
    const int n  = blockIdx.y;
    const int b  = blockIdx.z;
    const int tid = threadIdx.x;
    const int lane = tid & 63;
    const int wv   = tid >> 6;
    const int m0 = mt * 64;
    unsigned* sb = (unsigned*)(io + ((size_t)b * 768 + (size_t)n * 96) * 4096);

    for (int idx = tid; idx < 96 * 64; idx += NTH) {
        int i = idx >> 6, mm = idx & 63;
        int m = m0 + mm;
        const unsigned* row = sb + (size_t)i * 4096;
        ushort re = 0, im = 0;
        if (m == 0) { re = ((const ushort*)row)[0]; }
        else if (m == 2048) { re = ((const ushort*)row)[1]; }
        else if (m < 2048) { unsigned v = row[m]; re = (ushort)v; im = (ushort)(v >> 16); }
        xb[0][mm][i] = re;
        xb[1][mm][i] = im;
    }
    const float* W1r = w1_re + (size_t)n * 9216;
    const float* W1i = w1_im + (size_t)n * 9216;
    for (int idx = tid; idx < 9216; idx += NTH) {
        int i = idx / 96, o = idx - i * 96;
        wb[0][o][i] = f2bf(W1r[idx]);
        wb[1][o][i] = f2bf(W1i[idx]);
    }
    const int lc = lane & 15;
    float b1r[6], b1i[6], b2r[6], b2i[6];
#pragma unroll
    for (int nt = 0; nt < 6; ++nt) {
        b1r[nt] = b1_re[n * 96 + nt * 16 + lc];
        b1i[nt] = b1_im[n * 96 + nt * 16 + lc];
        b2r[nt] = b2_re[n * 96 + nt * 16 + lc];
        b2i[nt] = b2_im[n * 96 + nt * 16 + lc];
    }
    __syncthreads();

    const int mw = wv * 16;
    const int klr = 8 * (lane >> 4);
    const int mrow = mw + lc;

    f32x4 accR[6], accI[6];
    const f32x4 zero = {0.f, 0.f, 0.f, 0.f};
#pragma unroll
    for (int nt = 0; nt < 6; ++nt) { accR[nt] = zero; accI[nt] = zero; }

#pragma unroll
    for (int kk = 0; kk < 3; ++kk) {
        int k0 = kk * 32 + klr;
        short8 ar = *(const short8*)&xb[0][mrow][k0];
        short8 ai = *(const short8*)&xb[1][mrow][k0];
        short8 nai;
#pragma unroll
        for (int j = 0; j < 8; ++j) nai[j] = ai[j] ^ (short)0x8000;
#pragma unroll
        for (int nt = 0; nt < 6; ++nt) {
            short8 br = *(const short8*)&wb[0][nt * 16 + lc][k0];
            short8 bi = *(const short8*)&wb[1][nt * 16 + lc][k0];
            accR[nt] = __builtin_amdgcn_mfma_f32_16x16x32_bf16(ar,  br, accR[nt], 0, 0, 0);
            accR[nt] = __builtin_amdgcn_mfma_f32_16x16x32_bf16(nai, bi, accR[nt], 0, 0, 0);
            accI[nt] = __builtin_amdgcn_mfma_f32_16x16x32_bf16(ar,  bi, accI[nt], 0, 0, 0);
            accI[nt] = __builtin_amdgcn_mfma_f32_16x16x32_bf16(ai,  br, accI[nt], 0, 0, 0);
        }
    }
#pragma unroll
    for (int nt = 0; nt < 6; ++nt) {
#pragma unroll
        for (int q = 0; q < 4; ++q) {
            int m = mw + 4 * (lane >> 4) + q;
            float hr = fmaxf(accR[nt][q] + b1r[nt], 0.f);
            float hi2 = fmaxf(accI[nt][q] + b1i[nt], 0.f);
            xb[0][m][nt * 16 + lc] = f2bf(hr);
            xb[1][m][nt * 16 + lc] = f2bf(hi2);
        }
    }
    __syncthreads();

    const float* W2r = w2_re + (size_t)n * 9216;
    const float* W2i = w2_im + (size_t)n * 9216;
    for (int idx = tid; idx < 9216; idx += NTH) {
        int i = idx / 96, o = idx - i * 96;
        wb[0][o][i] = f2bf(W2r[idx]);
        wb[1][o][i] = f2bf(W2i[idx]);
    }
    __syncthreads();

#pragma unroll
    for (int nt = 0; nt < 6; ++nt) { accR[nt] = zero; accI[nt] = zero; }
#pragma unroll
    for (int kk = 0; kk < 3; ++kk) {
        int k0 = kk * 32 + klr;
        short8 ar = *(const short8*)&xb[0][mrow][k0];
        short8 ai = *(const short8*)&xb[1][mrow][k0];
        short8 nai;
#pragma unroll
        for (int j = 0; j < 8; ++j) nai[j] = ai[j] ^ (short)0x8000;
#pragma unroll
        for (int nt = 0; nt < 6; ++nt) {
            short8 br = *(const short8*)&wb[0][nt * 16 + lc][k0];
            short8 bi = *(const short8*)&wb[1][nt * 16 + lc][k0];
            accR[nt] = __builtin_amdgcn_mfma_f32_16x16x32_bf16(ar,  br, accR[nt], 0, 0, 0);
            accR[nt] = __builtin_amdgcn_mfma_f32_16x16x32_bf16(nai, bi, accR[nt], 0, 0, 0);
            accI[nt] = __builtin_amdgcn_mfma_f32_16x16x32_bf16(ar,  bi, accI[nt], 0, 0, 0);
            accI[nt] = __builtin_amdgcn_mfma_f32_16x16x32_bf16(ai,  br, accI[nt], 0, 0, 0);
        }
    }
#pragma unroll
    for (int nt = 0; nt < 6; ++nt) {
#pragma unroll
        for (int q = 0; q < 4; ++q) {
            int m = m0 + mw + 4 * (lane >> 4) + q;
            float vr = accR[nt][q] + b2r[nt];
            float vi = accI[nt][q] + b2i[nt];
            float sr = copysignf(fmaxf(fabsf(vr) - LAM, 0.f), vr);
            float si = copysignf(fmaxf(fabsf(vi) - LAM, 0.f), vi);
            unsigned* row = sb + (size_t)(nt * 16 + lc) * 4096;
            if (m == 0)          ((ushort*)row)[0] = f2bf(sr);
            else if (m == 2048)  ((ushort*)row)[1] = f2bf(sr);
            else if (m < 2048)   row[m] = (unsigned)f2bf(sr) | ((unsigned)f2bf(si) << 16);
        }
    }
}

// ---------------------------------------------------------------------------
// Inverse rfft per row (ortho) + residual add. Reads packed bf16 spectrum
// (8 KB head of the row), writes fp32 time signal (full 16 KB) in place.
// All spectrum reads happen in fused stage 1, before any store.
// ---------------------------------------------------------------------------
__global__ __launch_bounds__(NTH, 4) void k_irfft_add(const float* __restrict__ x,
                                                      float* __restrict__ io) {
    __shared__ float2 bufA[FFT_LDS_SZ];
    __shared__ float2 bufB[FFT_LDS_SZ];
    const int row = blockIdx.x;
    const float* xr = x + (size_t)row * 4096;
    float* orow = io + (size_t)row * 4096;
    const unsigned* srow = (const unsigned*)orow;
    const int tid = threadIdx.x;
    const float scale = 1.0f / 32.0f;

    // ---- fused: pre-twiddle pack + radix-8 stage 1 (Ns=1) from bf16 spectrum
    {
        float2 t[8], o[8];
        float s0, c0;
        __sincosf((float)M_PI * (float)tid / 2048.0f, &s0, &c0);
        float2 w = make_float2(c0, s0);
        const float2 stepw = make_float2(0.92387953251128674f, 0.38268343236508978f);
#pragma unroll
        for (int j = 0; j < 8; ++j) {
            const int k = tid + 256 * j;
            float Xr, Xi, Yr, Yi;
            if (k == 0) {
                unsigned v0 = srow[0];
                Xr = bf2f((ushort)v0); Xi = 0.f;
                Yr = bf2f((ushort)(v0 >> 16)); Yi = 0.f;
            } else {
                unsigned a  = srow[k];
                unsigned bq = srow[2048 - k];
                Xr = bf2f((ushort)a);  Xi = bf2f((ushort)(a >> 16));
                Yr = bf2f((ushort)bq); Yi = bf2f((ushort)(bq >> 16));
            }
            float Fer = 0.5f * (Xr + Yr), Fei = 0.5f * (Xi - Yi);
            float Dr  = 0.5f * (Xr - Yr), Di  = 0.5f * (Xi + Yi);
            float For = w.x * Dr - w.y * Di;
            float Foi = w.x * Di + w.y * Dr;
            t[j] = make_float2((Fer - Foi) * scale, (Fei + For) * scale);
            w = cmul(w, stepw);
        }
        radix8_bfly(t, o, 1.0f);
#pragma unroll
        for (int j = 0; j < 8; ++j)
            bufB[pad(8 * tid + j)] = o[j];
    }
    __syncthreads();
    radix8_stage(bufB, bufA, tid, 8, 1.0f);
    __syncthreads();
    radix8_stage(bufA, bufB, tid, 64, 1.0f);
    __syncthreads();

    // ---- fused radix-4 final (Ns=512) + residual add + store
#pragma unroll
    for (int it = 0; it < 2; ++it) {
        const int u = tid + 256 * it;
        float2 x0 = bufB[pad(u)];
        float2 x1 = bufB[pad(u + 512)];
        float2 x2 = bufB[pad(u + 1024)];
        float2 x3 = bufB[pad(u + 1536)];
        float ang = ((float)M_PI / 1024.0f) * (float)u;
        float s1, c1;
        __sincosf(ang, &s1, &c1);
        float2 w1 = make_float2(c1, s1);
        float2 w2 = cmul(w1, w1);
        float2 w3 = cmul(w2, w1);
        x1 = cmul(x1, w1); x2 = cmul(x2, w2); x3 = cmul(x3, w3);
        float2 apc = cadd(x0, x2), amc = csub(x0, x2);
        float2 bpd = cadd(x1, x3), bmd = csub(x1, x3);
        float2 e = cjrot(bmd, 1.0f);
        float2 y0 = cadd(apc, bpd);
        float2 y1 = cadd(amc, e);
        float2 y2 = csub(apc, bpd);
        float2 y3 = csub(amc, e);
        float2 xv0 = *(const float2*)(xr + 2 * u);
        float2 xv1 = *(const float2*)(xr + 2 * (u + 512));
        float2 xv2 = *(const float2*)(xr + 2 * (u + 1024));
        float2 xv3 = *(const float2*)(xr + 2 * (u + 1536));
        *(float2*)(orow + 2 * u)          = cadd(y0, xv0);
        *(float2*)(orow + 2 * (u + 512))  = cadd(y1, xv1);
        *(float2*)(orow + 2 * (u + 1024)) = cadd(y2, xv2);
        *(float2*)(orow + 2 * (u + 1536)) = cadd(y3, xv3);
    }
}

// ---------------------------------------------------------------------------
extern "C" void kernel_launch(void* const* d_in, const int* in_sizes, int n_in,
                              void* d_out, int out_size, void* d_ws, size_t ws_size,
                              hipStream_t stream) {
    const float* x     = (const float*)d_in[0];
    const float* w1_re = (const float*)d_in[1];
    const float* w1_im = (const float*)d_in[2];
    const float* w2_re = (const float*)d_in[3];
    const float* w2_im = (const float*)d_in[4];
    const float* b1_re = (const float*)d_in[5];
    const float* b1_im = (const float*)d_in[6];
    const float* b2_re = (const float*)d_in[7];
    const float* b2_im = (const float*)d_in[8];
    float* out = (float*)d_out;

    k_rfft_fwd<<<12288, NTH, 0, stream>>>(x, out);
    if (ws_size >= (size_t)WS_WT_BYTES) {
        ushort* wt = (ushort*)d_ws;
        k_prep<<<(294912 + NTH - 1) / NTH, NTH, 0, stream>>>(w1_re, w1_im, w2_re, w2_im, wt);
        k_mix11<<<dim3(33, 8, 16), NTHM, 0, stream>>>(out, wt, b1_re, b1_im, b2_re, b2_im);
    } else {
        k_mix_fallback<<<dim3(33, 8, 16), NTH, 0, stream>>>(out, w1_re, w1_im, w2_re, w2_im,
                                                            b1_re, b1_im, b2_re, b2_im);
    }
    k_irfft_add<<<12288, NTH, 0, stream>>>(x, out);
}

// Round 13
// 244.916 us; speedup vs baseline: 1.0184x; 1.0184x over previous
//
#include <hip/hip_runtime.h>
#include <math.h>

#define NTH 256
#define NTHM 128
#define LAM 0.01f
#define WS_WT_BYTES 589824   // 8n * 2L * 3kk * 6nt * 2ri * 64lane * 8 * 2B

typedef __attribute__((ext_vector_type(8))) short short8;
typedef __attribute__((ext_vector_type(8))) unsigned short ushort8;
typedef __attribute__((ext_vector_type(4))) float f32x4;
typedef __attribute__((ext_vector_type(4))) unsigned int uint4v;

__device__ __forceinline__ ushort f2bf(float f) {
    union { float f; unsigned u; } c; c.f = f;
    unsigned u = c.u;
    u += 0x7fffu + ((u >> 16) & 1u);   // round-to-nearest-even
    return (ushort)(u >> 16);
}
__device__ __forceinline__ float bf2f(ushort h) {
    union { unsigned u; float f; } c; c.u = ((unsigned)h) << 16; return c.f;
}

// Spectrum storage: packed bf16 (re lo16, im hi16), one uint per mode, in the
// first 8 KB of each row's 16 KB slot. Word 0 = {re(mode0) lo, re(mode2048) hi}.

// LDS index padding for FFT stages.
__device__ __forceinline__ int pad(int i) { return i + (i >> 3); }
#define FFT_LDS_SZ 2304

// ---- complex helpers -------------------------------------------------------
__device__ __forceinline__ float2 cadd(float2 a, float2 b) { return make_float2(a.x + b.x, a.y + b.y); }
__device__ __forceinline__ float2 csub(float2 a, float2 b) { return make_float2(a.x - b.x, a.y - b.y); }
__device__ __forceinline__ float2 cmul(float2 a, float2 b) { return make_float2(a.x * b.x - a.y * b.y, a.x * b.y + a.y * b.x); }
__device__ __forceinline__ float2 cjrot(float2 a, float sign) { return make_float2(-sign * a.y, sign * a.x); } // sign*i*a

// ---------------------------------------------------------------------------
// Radix-8 butterfly on registers (Ns=1 form: no input twiddle).
// ---------------------------------------------------------------------------
__device__ __forceinline__ void radix8_bfly(const float2 t[8], float2 o[8], float sign) {
    float2 apc = cadd(t[0], t[4]), amc = csub(t[0], t[4]);
    float2 bpd = cadd(t[2], t[6]), bmd = csub(t[2], t[6]);
    float2 e0 = cadd(apc, bpd), e2 = csub(apc, bpd);
    float2 jb = cjrot(bmd, sign);
    float2 e1 = cadd(amc, jb), e3 = csub(amc, jb);
    float2 apc2 = cadd(t[1], t[5]), amc2 = csub(t[1], t[5]);
    float2 bpd2 = cadd(t[3], t[7]), bmd2 = csub(t[3], t[7]);
    float2 q0 = cadd(apc2, bpd2), q2 = csub(apc2, bpd2);
    float2 jb2 = cjrot(bmd2, sign);
    float2 q1 = cadd(amc2, jb2), q3 = csub(amc2, jb2);
    const float H = 0.70710678118654752f;
    q1 = cmul(q1, make_float2(H, sign * H));
    q2 = cjrot(q2, sign);
    q3 = cmul(q3, make_float2(-H, sign * H));
    o[0] = cadd(e0, q0); o[1] = cadd(e1, q1); o[2] = cadd(e2, q2); o[3] = cadd(e3, q3);
    o[4] = csub(e0, q0); o[5] = csub(e1, q1); o[6] = csub(e2, q2); o[7] = csub(e3, q3);
}

// ---------------------------------------------------------------------------
// Middle radix-8 Stockham stage (LDS -> LDS), with input twiddles.
// ---------------------------------------------------------------------------
__device__ __forceinline__ void radix8_stage(const float2* __restrict__ src,
                                             float2* __restrict__ dst,
                                             int tid, int Ns, float sign) {
    const int u = tid;
    const int r = u & (Ns - 1);
    float2 t[8];
    t[0] = src[pad(u)];
    t[1] = src[pad(u + 256)];
    t[2] = src[pad(u + 512)];
    t[3] = src[pad(u + 768)];
    t[4] = src[pad(u + 1024)];
    t[5] = src[pad(u + 1280)];
    t[6] = src[pad(u + 1536)];
    t[7] = src[pad(u + 1792)];
    {
        float ang = sign * ((float)M_PI / (4.0f * (float)Ns)) * (float)r;
        float s1, c1;
        __sincosf(ang, &s1, &c1);
        float2 w1 = make_float2(c1, s1);
        float2 w2 = cmul(w1, w1);
        float2 w3 = cmul(w2, w1);
        float2 w4 = cmul(w2, w2);
        float2 w5 = cmul(w4, w1);
        float2 w6 = cmul(w4, w2);
        float2 w7 = cmul(w4, w3);
        t[1] = cmul(t[1], w1); t[2] = cmul(t[2], w2); t[3] = cmul(t[3], w3);
        t[4] = cmul(t[4], w4); t[5] = cmul(t[5], w5); t[6] = cmul(t[6], w6);
        t[7] = cmul(t[7], w7);
    }
    float2 o[8];
    radix8_bfly(t, o, sign);
    const int d = ((u - r) << 3) + r;
    dst[pad(d)]          = o[0];
    dst[pad(d + Ns)]     = o[1];
    dst[pad(d + 2 * Ns)] = o[2];
    dst[pad(d + 3 * Ns)] = o[3];
    dst[pad(d + 4 * Ns)] = o[4];
    dst[pad(d + 5 * Ns)] = o[5];
    dst[pad(d + 6 * Ns)] = o[6];
    dst[pad(d + 7 * Ns)] = o[7];
}

__device__ __forceinline__ void radix4_final(const float2* __restrict__ src,
                                             float2* __restrict__ dst,
                                             int tid, float sign) {
    for (int u = tid; u < 512; u += NTH) {
        float2 x0 = src[pad(u)];
        float2 x1 = src[pad(u + 512)];
        float2 x2 = src[pad(u + 1024)];
        float2 x3 = src[pad(u + 1536)];
        float ang = sign * ((float)M_PI / 1024.0f) * (float)u;
        float s1, c1;
        __sincosf(ang, &s1, &c1);
        float2 w1 = make_float2(c1, s1);
        float2 w2 = cmul(w1, w1);
        float2 w3 = cmul(w2, w1);
        x1 = cmul(x1, w1); x2 = cmul(x2, w2); x3 = cmul(x3, w3);
        float2 apc = cadd(x0, x2), amc = csub(x0, x2);
        float2 bpd = cadd(x1, x3), bmd = csub(x1, x3);
        float2 e = cjrot(bmd, sign);
        dst[pad(u)]        = cadd(apc, bpd);
        dst[pad(u + 512)]  = cadd(amc, e);
        dst[pad(u + 1024)] = csub(apc, bpd);
        dst[pad(u + 1536)] = csub(amc, e);
    }
}

// ---------------------------------------------------------------------------
// Forward rfft per row (ortho); output = packed bf16 spectrum (8 KB / row).
// ---------------------------------------------------------------------------
__global__ __launch_bounds__(NTH, 4) void k_rfft_fwd(const float* __restrict__ x,
                                                     float* __restrict__ out) {
    __shared__ float2 bufA[FFT_LDS_SZ];
    __shared__ float2 bufB[FFT_LDS_SZ];
    const int row = blockIdx.x;
    const float* xr = x + (size_t)row * 4096;
    unsigned* srow = (unsigned*)(out + (size_t)row * 4096);
    const int tid = threadIdx.x;

    // ---- fused stage 1 (radix-8, Ns=1) straight from global
    {
        float2 t[8], o[8];
#pragma unroll
        for (int j = 0; j < 8; ++j)
            t[j] = *(const float2*)(xr + 2 * (tid + 256 * j));
        radix8_bfly(t, o, -1.0f);
#pragma unroll
        for (int j = 0; j < 8; ++j)
            bufB[pad(8 * tid + j)] = o[j];
    }
    __syncthreads();
    radix8_stage(bufB, bufA, tid, 8, -1.0f);
    __syncthreads();
    radix8_stage(bufA, bufB, tid, 64, -1.0f);
    __syncthreads();
    radix4_final(bufB, bufA, tid, -1.0f);
    __syncthreads();
    float2* Z = bufA;

    // ---- pack to bf16; twiddle chained by rotation of -pi/8 per iteration
    const float scale = 1.0f / 64.0f;
    float s0, c0;
    __sincosf(-(float)M_PI * (float)tid / 2048.0f, &s0, &c0);
    float2 w = make_float2(c0, s0);
    const float2 stepw = make_float2(0.92387953251128674f, -0.38268343236508978f);
    for (int k = tid; k <= 2048; k += NTH) {
        float2 zk = Z[pad(k & 2047)];
        float2 zn = Z[pad((2048 - k) & 2047)];
        float Ar = 0.5f * (zk.x + zn.x), Ai = 0.5f * (zk.y - zn.y);
        float Br = 0.5f * (zk.x - zn.x), Bi = 0.5f * (zk.y + zn.y);
        float wBr = w.x * Br - w.y * Bi;
        float wBi = w.x * Bi + w.y * Br;
        float Xr = (Ar + wBi) * scale;
        float Xi = (Ai - wBr) * scale;
        if (k == 0)          ((ushort*)srow)[0] = f2bf(Xr);
        else if (k == 2048)  ((ushort*)srow)[1] = f2bf(Xr);
        else                 srow[k] = (unsigned)f2bf(Xr) | ((unsigned)f2bf(Xi) << 16);
        w = cmul(w, stepw);
    }
}

// ---------------------------------------------------------------------------
// Weight preprocessing: fp32 W -> bf16 FRAGMENT-ORDERED layout:
//   wtf[n][L][kk][nt][ri][lane][8]  (lane = hi*16+lc)
// Each mixer weight load = 64 lanes x 16 B = 1 KB fully contiguous.
// Fragment (n,L,kk,nt,ri,lane,j) = W_L,ri[n][i][o], o = nt*16+lc,
// i = kk*32 + hi*8 + j.
// ---------------------------------------------------------------------------
__global__ __launch_bounds__(NTH) void k_prep(
    const float* __restrict__ w1_re, const float* __restrict__ w1_im,
    const float* __restrict__ w2_re, const float* __restrict__ w2_im,
    ushort* __restrict__ wt) {
    int gid = blockIdx.x * NTH + threadIdx.x;   // 0 .. 294911
    if (gid >= 294912) return;
    int j    = gid & 7;
    int lane = (gid >> 3) & 63;
    int ri   = (gid >> 9) & 1;
    int nt   = (gid >> 10) % 6;
    int kk   = (gid / 6144) % 3;
    int L    = (gid / 18432) & 1;
    int n    = gid / 36864;
    int lc = lane & 15, hi = lane >> 4;
    int o = nt * 16 + lc;
    int i = kk * 32 + hi * 8 + j;
    const float* src = (L == 0) ? ((ri == 0) ? w1_re : w1_im)
                                : ((ri == 0) ? w2_re : w2_im);
    wt[gid] = f2bf(src[(n * 96 + i) * 96 + o]);
}

// ---------------------------------------------------------------------------
// MFMA mixer v12: mix11 + fragment-ordered weights (1-KB contiguous loads).
// Grid (33, 8, 16) x 128 thr (2 waves x 32 modes), barrier-free.
// ---------------------------------------------------------------------------
__global__ __launch_bounds__(NTHM, 2) void k_mix12(
    float* __restrict__ io, const ushort* __restrict__ wt,
    const float* __restrict__ b1_re, const float* __restrict__ b1_im,
    const float* __restrict__ b2_re, const float* __restrict__ b2_im) {
    __shared__ __align__(16) ushort xb[2][64][104];   // 26624 B (reused as out-staging)

    const int mt = blockIdx.x;
    const int n  = blockIdx.y;
    const int b  = blockIdx.z;
    const int tid  = threadIdx.x;
    const int lane = tid & 63;
    const int wv   = tid >> 6;            // 0..1
    const int m0 = mt * 64;
    const int ws0 = wv * 32;              // wave's private 32-row stripe
    unsigned* sb = (unsigned*)(io + ((size_t)b * 768 + (size_t)n * 96) * 4096);

    const int lc = lane & 15;
    const int hi = lane >> 4;
    const int ll = lane & 31;             // mode within wave stripe
    const int ch = lane >> 5;             // channel phase (0/1)
    const int mbase = m0 + ws0;
    const bool interior = (mbase >= 1) && (mbase + 31 < 2048);

    // ---- stage: 48 loads issued up-front, then unpack to LDS
    {
        const int m = mbase + ll;
        const unsigned* src = sb + ((m >= 1 && m < 2048) ? m : 0);
        unsigned v[48];
#pragma unroll
        for (int t = 0; t < 48; ++t)
            v[t] = src[(size_t)(ch + 2 * t) * 4096];
        if (interior) {
#pragma unroll
            for (int t = 0; t < 48; ++t) {
                const int i = ch + 2 * t;
                xb[0][ws0 + ll][i] = (ushort)v[t];
                xb[1][ws0 + ll][i] = (ushort)(v[t] >> 16);
            }
        } else {
#pragma unroll
            for (int t = 0; t < 48; ++t) {
                const int i = ch + 2 * t;
                unsigned w = v[t];
                ushort lo = (ushort)w, h16 = (ushort)(w >> 16);
                ushort re = (m == 2048) ? h16 : (m < 2048 ? lo : (ushort)0);
                ushort im = (m >= 1 && m < 2048) ? h16 : (ushort)0;
                xb[0][ws0 + ll][i] = re;
                xb[1][ws0 + ll][i] = im;
            }
        }
    }

    const int mr0 = ws0 + lc;
    const int mr1 = ws0 + 16 + lc;
    // fragment-ordered weight base: wtf[n][L][kk][nt][ri][lane][8]
    const ushort* wn  = wt + (size_t)(n * 2 + 0) * 18432 + lane * 8;  // layer 1
    const ushort* wn2 = wt + (size_t)(n * 2 + 1) * 18432 + lane * 8;  // layer 2

    float b1r[6], b1i[6];
#pragma unroll
    for (int nt = 0; nt < 6; ++nt) {
        b1r[nt] = b1_re[n * 96 + nt * 16 + lc];
        b1i[nt] = b1_im[n * 96 + nt * 16 + lc];
    }

    f32x4 accR[2][6], accI[2][6];
    const f32x4 zero = {0.f, 0.f, 0.f, 0.f};
#pragma unroll
    for (int t2 = 0; t2 < 2; ++t2)
#pragma unroll
        for (int nt = 0; nt < 6; ++nt) { accR[t2][nt] = zero; accI[t2][nt] = zero; }

    // weight ping-pong buffers (indices compile-time after unroll)
    short8 wr[2][6], wi[2][6];
#define LOADW(baseL, kkv, buf)                                             \
    {                                                                      \
        _Pragma("unroll")                                                  \
        for (int nt_ = 0; nt_ < 6; ++nt_) {                                \
            const ushort* wp_ = (baseL) + ((kkv) * 6 + nt_) * 1024;        \
            wr[buf][nt_] = *(const short8*)(wp_);                          \
            wi[buf][nt_] = *(const short8*)(wp_ + 512);                    \
        }                                                                  \
    }

    // ---- layer 1: double-buffered weight batches
    LOADW(wn, 0, 0);
#pragma unroll
    for (int kk = 0; kk < 3; ++kk) {
        const int cur = kk & 1;
        if (kk < 2) LOADW(wn, kk + 1, cur ^ 1);     // in flight during MFMAs
        const int k0 = kk * 32 + 8 * hi;
        short8 arA = *(const short8*)&xb[0][mr0][k0];
        short8 aiA = *(const short8*)&xb[1][mr0][k0];
        short8 arB = *(const short8*)&xb[0][mr1][k0];
        short8 aiB = *(const short8*)&xb[1][mr1][k0];
        short8 naiA, naiB;
#pragma unroll
        for (int j = 0; j < 8; ++j) { naiA[j] = aiA[j] ^ (short)0x8000; naiB[j] = aiB[j] ^ (short)0x8000; }
#pragma unroll
        for (int nt = 0; nt < 6; ++nt) {
            accR[0][nt] = __builtin_amdgcn_mfma_f32_16x16x32_bf16(arA,  wr[cur][nt], accR[0][nt], 0, 0, 0);
            accR[0][nt] = __builtin_amdgcn_mfma_f32_16x16x32_bf16(naiA, wi[cur][nt], accR[0][nt], 0, 0, 0);
            accI[0][nt] = __builtin_amdgcn_mfma_f32_16x16x32_bf16(arA,  wi[cur][nt], accI[0][nt], 0, 0, 0);
            accI[0][nt] = __builtin_amdgcn_mfma_f32_16x16x32_bf16(aiA,  wr[cur][nt], accI[0][nt], 0, 0, 0);
            accR[1][nt] = __builtin_amdgcn_mfma_f32_16x16x32_bf16(arB,  wr[cur][nt], accR[1][nt], 0, 0, 0);
            accR[1][nt] = __builtin_amdgcn_mfma_f32_16x16x32_bf16(naiB, wi[cur][nt], accR[1][nt], 0, 0, 0);
            accI[1][nt] = __builtin_amdgcn_mfma_f32_16x16x32_bf16(arB,  wi[cur][nt], accI[1][nt], 0, 0, 0);
            accI[1][nt] = __builtin_amdgcn_mfma_f32_16x16x32_bf16(aiB,  wr[cur][nt], accI[1][nt], 0, 0, 0);
        }
    }

    // prefetch layer-2 batch 0 before crelu (hides under VALU+LDS below)
    LOADW(wn2, 0, 0);

    // crelu -> h into own stripes (same-wave LDS dependency only)
#pragma unroll
    for (int t2 = 0; t2 < 2; ++t2)
#pragma unroll
        for (int nt = 0; nt < 6; ++nt) {
#pragma unroll
            for (int q = 0; q < 4; ++q) {
                int mm = ws0 + t2 * 16 + 4 * hi + q;
                xb[0][mm][nt * 16 + lc] = f2bf(fmaxf(accR[t2][nt][q] + b1r[nt], 0.f));
                xb[1][mm][nt * 16 + lc] = f2bf(fmaxf(accI[t2][nt][q] + b1i[nt], 0.f));
            }
        }

    // ---- layer 2: double-buffered weight batches
#pragma unroll
    for (int t2 = 0; t2 < 2; ++t2)
#pragma unroll
        for (int nt = 0; nt < 6; ++nt) { accR[t2][nt] = zero; accI[t2][nt] = zero; }
#pragma unroll
    for (int kk = 0; kk < 3; ++kk) {
        const int cur = kk & 1;
        if (kk < 2) LOADW(wn2, kk + 1, cur ^ 1);
        const int k0 = kk * 32 + 8 * hi;
        short8 arA = *(const short8*)&xb[0][mr0][k0];
        short8 aiA = *(const short8*)&xb[1][mr0][k0];
        short8 arB = *(const short8*)&xb[0][mr1][k0];
        short8 aiB = *(const short8*)&xb[1][mr1][k0];
        short8 naiA, naiB;
#pragma unroll
        for (int j = 0; j < 8; ++j) { naiA[j] = aiA[j] ^ (short)0x8000; naiB[j] = aiB[j] ^ (short)0x8000; }
#pragma unroll
        for (int nt = 0; nt < 6; ++nt) {
            accR[0][nt] = __builtin_amdgcn_mfma_f32_16x16x32_bf16(arA,  wr[cur][nt], accR[0][nt], 0, 0, 0);
            accR[0][nt] = __builtin_amdgcn_mfma_f32_16x16x32_bf16(naiA, wi[cur][nt], accR[0][nt], 0, 0, 0);
            accI[0][nt] = __builtin_amdgcn_mfma_f32_16x16x32_bf16(arA,  wi[cur][nt], accI[0][nt], 0, 0, 0);
            accI[0][nt] = __builtin_amdgcn_mfma_f32_16x16x32_bf16(aiA,  wr[cur][nt], accI[0][nt], 0, 0, 0);
            accR[1][nt] = __builtin_amdgcn_mfma_f32_16x16x32_bf16(arB,  wr[cur][nt], accR[1][nt], 0, 0, 0);
            accR[1][nt] = __builtin_amdgcn_mfma_f32_16x16x32_bf16(naiB, wi[cur][nt], accR[1][nt], 0, 0, 0);
            accI[1][nt] = __builtin_amdgcn_mfma_f32_16x16x32_bf16(arB,  wi[cur][nt], accI[1][nt], 0, 0, 0);
            accI[1][nt] = __builtin_amdgcn_mfma_f32_16x16x32_bf16(aiB,  wr[cur][nt], accI[1][nt], 0, 0, 0);
        }
    }
#undef LOADW

    // ---- softshrink + store
    float b2r[6], b2i[6];
#pragma unroll
    for (int nt = 0; nt < 6; ++nt) {
        b2r[nt] = b2_re[n * 96 + nt * 16 + lc];
        b2i[nt] = b2_im[n * 96 + nt * 16 + lc];
    }
    if (interior) {
        // wave-private out-staging: chans 0..47 in this wave's plane-0 chunk,
        // chans 48..95 in its plane-1 chunk ([48][33] uints each, 1584<=1664).
        unsigned* ob0 = (unsigned*)&xb[0][ws0][0];
        unsigned* ob1 = (unsigned*)&xb[1][ws0][0];
#pragma unroll
        for (int t2 = 0; t2 < 2; ++t2)
#pragma unroll
            for (int nt = 0; nt < 6; ++nt) {
                unsigned* obp = (nt < 3) ? ob0 : ob1;
                const int crow = nt * 16 + lc - ((nt < 3) ? 0 : 48);
#pragma unroll
                for (int q = 0; q < 4; ++q) {
                    float vr = accR[t2][nt][q] + b2r[nt];
                    float vi = accI[t2][nt][q] + b2i[nt];
                    float sr = copysignf(fmaxf(fabsf(vr) - LAM, 0.f), vr);
                    float si = copysignf(fmaxf(fabsf(vi) - LAM, 0.f), vi);
                    obp[crow * 33 + (t2 * 16 + 4 * hi + q)] =
                        (unsigned)f2bf(sr) | ((unsigned)f2bf(si) << 16);
                }
            }
        // linear 128-B stores: 12 instructions x (8 rows x 128 B)
#pragma unroll
        for (int s = 0; s < 12; ++s) {
            const int g   = s * 64 + lane;     // 4-uint group, 8 per chan-row
            const int row = g >> 3;            // chan 0..95
            const int wih = g & 7;             // which 16 B within the 128 B
            const unsigned* lsrc = ((row < 48) ? ob0 : ob1) +
                                   (row - ((row < 48) ? 0 : 48)) * 33 + wih * 4;
            uint4v pk;
            pk[0] = lsrc[0]; pk[1] = lsrc[1]; pk[2] = lsrc[2]; pk[3] = lsrc[3];
            *(uint4v*)(sb + (size_t)row * 4096 + mbase + wih * 4) = pk;
        }
    } else {
        // scalar edge path (modes 0 / >=2048)
#pragma unroll
        for (int t2 = 0; t2 < 2; ++t2) {
            const int mq = mbase + t2 * 16 + 4 * hi;
#pragma unroll
            for (int nt = 0; nt < 6; ++nt) {
                float sr[4], si[4];
#pragma unroll
                for (int q = 0; q < 4; ++q) {
                    float vr = accR[t2][nt][q] + b2r[nt];
                    float vi = accI[t2][nt][q] + b2i[nt];
                    sr[q] = copysignf(fmaxf(fabsf(vr) - LAM, 0.f), vr);
                    si[q] = copysignf(fmaxf(fabsf(vi) - LAM, 0.f), vi);
                }
                unsigned* row = sb + (size_t)(nt * 16 + lc) * 4096;
#pragma unroll
                for (int q = 0; q < 4; ++q) {
                    int m = mq + q;
                    if (m == 0)          ((ushort*)row)[0] = f2bf(sr[q]);
                    else if (m == 2048)  ((ushort*)row)[1] = f2bf(sr[q]);
                    else if (m < 2048)   row[m] = (unsigned)f2bf(sr[q]) | ((unsigned)f2bf(si[q]) << 16);
                }
            }
        }
    }
}

// ---------------------------------------------------------------------------
// Fallback mixer (no ws dependency), bf16 packed spectrum io.
// ---------------------------------------------------------------------------
__global__ __launch_bounds__(NTH) void k_mix_fallback(
    float* __restrict__ io,
    const float* __restrict__ w1_re, const float* __restrict__ w1_im,
    const float* __restrict__ w2_re, const float* __restrict__ w2_im,
    const float* __restrict__ b1_re, const float* __restrict__ b1_im,
    const float* __restrict__ b2_re, const float* __restrict__ b2_im) {
    __shared__ __align__(16) ushort xb[2][64][96];
    __shared__ __align__(16) ushort wb[2][96][104];

    const int mt = blockIdx.x;
    const int n  = blockIdx.y;
    const int b  = blockIdx.z;
    const int tid = threadIdx.x;
    const int lane = tid & 63;
    const int wv   = tid >> 6;
    const int m0 = mt * 64;
    unsigned* sb = (unsigned*)(io + ((size_t)b * 768 + (size_t)n * 96) * 4096);

    for (int idx = tid; idx < 96 * 64; idx += NTH) {
        int i = idx >> 6, mm = idx & 63;
        int m = m0 + mm;
        const unsigned* row = sb + (size_t)i * 4096;
        ushort re = 0, im = 0;
        if (m == 0) { re = ((const ushort*)row)[0]; }
        else if (m == 2048) { re = ((const ushort*)row)[1]; }
        else if (m < 2048) { unsigned v = row[m]; re = (ushort)v; im = (ushort)(v >> 16); }
        xb[0][mm][i] = re;
        xb[1][mm][i] = im;
    }
    const float* W1r = w1_re + (size_t)n * 9216;
    const float* W1i = w1_im + (size_t)n * 9216;
    for (int idx = tid; idx < 9216; idx += NTH) {
        int i = idx / 96, o = idx - i * 96;
        wb[0][o][i] = f2bf(W1r[idx]);
        wb[1][o][i] = f2bf(W1i[idx]);
    }
    const int lc = lane & 15;
    float b1r[6], b1i[6], b2r[6], b2i[6];
#pragma unroll
    for (int nt = 0; nt < 6; ++nt) {
        b1r[nt] = b1_re[n * 96 + nt * 16 + lc];
        b1i[nt] = b1_im[n * 96 + nt * 16 + lc];
        b2r[nt] = b2_re[n * 96 + nt * 16 + lc];
        b2i[nt] = b2_im[n * 96 + nt * 16 + lc];
    }
    __syncthreads();

    const int mw = wv * 16;
    const int klr = 8 * (lane >> 4);
    const int mrow = mw + lc;

    f32x4 accR[6], accI[6];
    const f32x4 zero = {0.f, 0.f, 0.f, 0.f};
#pragma unroll
    for (int nt = 0; nt < 6; ++nt) { accR[nt] = zero; accI[nt] = zero; }

#pragma unroll
    for (int kk = 0; kk < 3; ++kk) {
        int k0 = kk * 32 + klr;
        short8 ar = *(const short8*)&xb[0][mrow][k0];
        short8 ai = *(const short8*)&xb[1][mrow][k0];
        short8 nai;
#pragma unroll
        for (int j = 0; j < 8; ++j) nai[j] = ai[j] ^ (short)0x8000;
#pragma unroll
        for (int nt = 0; nt < 6; ++nt) {
            short8 br = *(const short8*)&wb[0][nt * 16 + lc][k0];
            short8 bi = *(const short8*)&wb[1][nt * 16 + lc][k0];
            accR[nt] = __builtin_amdgcn_mfma_f32_16x16x32_bf16(ar,  br, accR[nt], 0, 0, 0);
            accR[nt] = __builtin_amdgcn_mfma_f32_16x16x32_bf16(nai, bi, accR[nt], 0, 0, 0);
            accI[nt] = __builtin_amdgcn_mfma_f32_16x16x32_bf16(ar,  bi, accI[nt], 0, 0, 0);
            accI[nt] = __builtin_amdgcn_mfma_f32_16x16x32_bf16(ai,  br, accI[nt], 0, 0, 0);
        }
    }
#pragma unroll
    for (int nt = 0; nt < 6; ++nt) {
#pragma unroll
        for (int q = 0; q < 4; ++q) {
            int m = mw + 4 * (lane >> 4) + q;
            float hr = fmaxf(accR[nt][q] + b1r[nt], 0.f);
            float hi2 = fmaxf(accI[nt][q] + b1i[nt], 0.f);
            xb[0][m][nt * 16 + lc] = f2bf(hr);
            xb[1][m][nt * 16 + lc] = f2bf(hi2);
        }
    }
    __syncthreads();

    const float* W2r = w2_re + (size_t)n * 9216;
    const float* W2i = w2_im + (size_t)n * 9216;
    for (int idx = tid; idx < 9216; idx += NTH) {
        int i = idx / 96, o = idx - i * 96;
        wb[0][o][i] = f2bf(W2r[idx]);
        wb[1][o][i] = f2bf(W2i[idx]);
    }
    __syncthreads();

#pragma unroll
    for (int nt = 0; nt < 6; ++nt) { accR[nt] = zero; accI[nt] = zero; }
#pragma unroll
    for (int kk = 0; kk < 3; ++kk) {
        int k0 = kk * 32 + klr;
        short8 ar = *(const short8*)&xb[0][mrow][k0];
        short8 ai = *(const short8*)&xb[1][mrow][k0];
        short8 nai;
#pragma unroll
        for (int j = 0; j < 8; ++j) nai[j] = ai[j] ^ (short)0x8000;
#pragma unroll
        for (int nt = 0; nt < 6; ++nt) {
            short8 br = *(const short8*)&wb[0][nt * 16 + lc][k0];
            short8 bi = *(const short8*)&wb[1][nt * 16 + lc][k0];
            accR[nt] = __builtin_amdgcn_mfma_f32_16x16x32_bf16(ar,  br, accR[nt], 0, 0, 0);
            accR[nt] = __builtin_amdgcn_mfma_f32_16x16x32_bf16(nai, bi, accR[nt], 0, 0, 0);
            accI[nt] = __builtin_amdgcn_mfma_f32_16x16x32_bf16(ar,  bi, accI[nt], 0, 0, 0);
            accI[nt] = __builtin_amdgcn_mfma_f32_16x16x32_bf16(ai,  br, accI[nt], 0, 0, 0);
        }
    }
#pragma unroll
    for (int nt = 0; nt < 6; ++nt) {
#pragma unroll
        for (int q = 0; q < 4; ++q) {
            int m = m0 + mw + 4 * (lane >> 4) + q;
            float vr = accR[nt][q] + b2r[nt];
            float vi = accI[nt][q] + b2i[nt];
            float sr = copysignf(fmaxf(fabsf(vr) - LAM, 0.f), vr);
            float si = copysignf(fmaxf(fabsf(vi) - LAM, 0.f), vi);
            unsigned* row = sb + (size_t)(nt * 16 + lc) * 4096;
            if (m == 0)          ((ushort*)row)[0] = f2bf(sr);
            else if (m == 2048)  ((ushort*)row)[1] = f2bf(sr);
            else if (m < 2048)   row[m] = (unsigned)f2bf(sr) | ((unsigned)f2bf(si) << 16);
        }
    }
}

// ---------------------------------------------------------------------------
// Inverse rfft per row (ortho) + residual add. Reads packed bf16 spectrum
// (8 KB head of the row), writes fp32 time signal (full 16 KB) in place.
// All spectrum reads happen in fused stage 1, before any store.
// ---------------------------------------------------------------------------
__global__ __launch_bounds__(NTH, 4) void k_irfft_add(const float* __restrict__ x,
                                                      float* __restrict__ io) {
    __shared__ float2 bufA[FFT_LDS_SZ];
    __shared__ float2 bufB[FFT_LDS_SZ];
    const int row = blockIdx.x;
    const float* xr = x + (size_t)row * 4096;
    float* orow = io + (size_t)row * 4096;
    const unsigned* srow = (const unsigned*)orow;
    const int tid = threadIdx.x;
    const float scale = 1.0f / 32.0f;

    // ---- fused: pre-twiddle pack + radix-8 stage 1 (Ns=1) from bf16 spectrum
    {
        float2 t[8], o[8];
        float s0, c0;
        __sincosf((float)M_PI * (float)tid / 2048.0f, &s0, &c0);
        float2 w = make_float2(c0, s0);
        const float2 stepw = make_float2(0.92387953251128674f, 0.38268343236508978f);
#pragma unroll
        for (int j = 0; j < 8; ++j) {
            const int k = tid + 256 * j;
            float Xr, Xi, Yr, Yi;
            if (k == 0) {
                unsigned v0 = srow[0];
                Xr = bf2f((ushort)v0); Xi = 0.f;
                Yr = bf2f((ushort)(v0 >> 16)); Yi = 0.f;
            } else {
                unsigned a  = srow[k];
                unsigned bq = srow[2048 - k];
                Xr = bf2f((ushort)a);  Xi = bf2f((ushort)(a >> 16));
                Yr = bf2f((ushort)bq); Yi = bf2f((ushort)(bq >> 16));
            }
            float Fer = 0.5f * (Xr + Yr), Fei = 0.5f * (Xi - Yi);
            float Dr  = 0.5f * (Xr - Yr), Di  = 0.5f * (Xi + Yi);
            float For = w.x * Dr - w.y * Di;
            float Foi = w.x * Di + w.y * Dr;
            t[j] = make_float2((Fer - Foi) * scale, (Fei + For) * scale);
            w = cmul(w, stepw);
        }
        radix8_bfly(t, o, 1.0f);
#pragma unroll
        for (int j = 0; j < 8; ++j)
            bufB[pad(8 * tid + j)] = o[j];
    }
    __syncthreads();
    radix8_stage(bufB, bufA, tid, 8, 1.0f);
    __syncthreads();
    radix8_stage(bufA, bufB, tid, 64, 1.0f);
    __syncthreads();

    // ---- fused radix-4 final (Ns=512) + residual add + store
#pragma unroll
    for (int it = 0; it < 2; ++it) {
        const int u = tid + 256 * it;
        float2 x0 = bufB[pad(u)];
        float2 x1 = bufB[pad(u + 512)];
        float2 x2 = bufB[pad(u + 1024)];
        float2 x3 = bufB[pad(u + 1536)];
        float ang = ((float)M_PI / 1024.0f) * (float)u;
        float s1, c1;
        __sincosf(ang, &s1, &c1);
        float2 w1 = make_float2(c1, s1);
        float2 w2 = cmul(w1, w1);
        float2 w3 = cmul(w2, w1);
        x1 = cmul(x1, w1); x2 = cmul(x2, w2); x3 = cmul(x3, w3);
        float2 apc = cadd(x0, x2), amc = csub(x0, x2);
        float2 bpd = cadd(x1, x3), bmd = csub(x1, x3);
        float2 e = cjrot(bmd, 1.0f);
        float2 y0 = cadd(apc, bpd);
        float2 y1 = cadd(amc, e);
        float2 y2 = csub(apc, bpd);
        float2 y3 = csub(amc, e);
        float2 xv0 = *(const float2*)(xr + 2 * u);
        float2 xv1 = *(const float2*)(xr + 2 * (u + 512));
        float2 xv2 = *(const float2*)(xr + 2 * (u + 1024));
        float2 xv3 = *(const float2*)(xr + 2 * (u + 1536));
        *(float2*)(orow + 2 * u)          = cadd(y0, xv0);
        *(float2*)(orow + 2 * (u + 512))  = cadd(y1, xv1);
        *(float2*)(orow + 2 * (u + 1024)) = cadd(y2, xv2);
        *(float2*)(orow + 2 * (u + 1536)) = cadd(y3, xv3);
    }
}

// ---------------------------------------------------------------------------
extern "C" void kernel_launch(void* const* d_in, const int* in_sizes, int n_in,
                              void* d_out, int out_size, void* d_ws, size_t ws_size,
                              hipStream_t stream) {
    const float* x     = (const float*)d_in[0];
    const float* w1_re = (const float*)d_in[1];
    const float* w1_im = (const float*)d_in[2];
    const float* w2_re = (const float*)d_in[3];
    const float* w2_im = (const float*)d_in[4];
    const float* b1_re = (const float*)d_in[5];
    const float* b1_im = (const float*)d_in[6];
    const float* b2_re = (const float*)d_in[7];
    const float* b2_im = (const float*)d_in[8];
    float* out = (float*)d_out;

    k_rfft_fwd<<<12288, NTH, 0, stream>>>(x, out);
    if (ws_size >= (size_t)WS_WT_BYTES) {
        ushort* wt = (ushort*)d_ws;
        k_prep<<<(294912 + NTH - 1) / NTH, NTH, 0, stream>>>(w1_re, w1_im, w2_re, w2_im, wt);
        k_mix12<<<dim3(33, 8, 16), NTHM, 0, stream>>>(out, wt, b1_re, b1_im, b2_re, b2_im);
    } else {
        k_mix_fallback<<<dim3(33, 8, 16), NTH, 0, stream>>>(out, w1_re, w1_im, w2_re, w2_im,
                                                            b1_re, b1_im, b2_re, b2_im);
    }
    k_irfft_add<<<12288, NTH, 0, stream>>>(x, out);
}